// Round 2
// 1387.441 us; speedup vs baseline: 1.2927x; 1.2927x over previous
//
#include <hip/hip_runtime.h>
#include <hip/hip_bf16.h>

#define BB 512
#define SS 2048
#define VV 29
#define HH 128

__device__ __forceinline__ float fast_tanh(float z) {
    // tanh(z) = sign(z) * (1 - 2e/(1+e)),  e = exp(-2|z|)  -- identical to round-1
    float az = fabsf(z);
    float e  = __expf(-2.0f * az);
    float r  = 1.0f - 2.0f * e * __builtin_amdgcn_rcpf(1.0f + e);
    return copysignf(r, z);
}

// One block per batch row. 256 threads = split-K x2 over the h-dot:
//   thread (i, g): partial_g[i] = sum_{j in g-half} We_hh[i][64g+j] * h[64g+j]
//   g0 also does x-proj v=0..14 + bias; g1 does x-proj v=15..28.
// Two barriers/step (partial exchange, h publish). 2048 waves -> 2 waves/SIMD.
// Decoder: single wave, h in lanes, __shfl broadcast, zero barriers.
// Decoder fixed-point shortcut: dec_in is constant across steps, so the
// decoder is a fixed-point iteration h <- tanh(c + W h). Once |dh| < 1e-6
// across all lanes (contraction => held-output error ~1e-5, far under the
// measured 3.9e-3 absmax), stop iterating and bulk-fill the remaining (t,:)
// rows with the fixed point via fully-coalesced dwordx4 stores. Fallback if
// it never converges: identical to the previous (1790 us) kernel.
__global__ __launch_bounds__(256) void rnn_fused(
    const float* __restrict__ x,      // (B,S,V)
    const float* __restrict__ We_ih,  // (H,V)
    const float* __restrict__ We_hh,  // (H,H)
    const float* __restrict__ be_ih,  // (H)
    const float* __restrict__ be_hh,  // (H)
    const float* __restrict__ Wd_ih,  // (V,H)
    const float* __restrict__ Wd_hh,  // (V,V)
    const float* __restrict__ bd_ih,  // (V)
    const float* __restrict__ bd_hh,  // (V)
    float* __restrict__ out)          // (B,S,V)
{
    const int b   = blockIdx.x;
    const int tid = threadIdx.x;
    const int i   = tid & 127;   // h index
    const int g   = tid >> 7;    // K-half

    __shared__ float hbuf[2][HH];
    __shared__ float xbuf[2][32];   // slots 29..31 stay 0
    __shared__ float part[HH];

    // ---- weights to registers ----
    float w[64];
    const float* wrow = We_hh + i * HH + g * 64;
    #pragma unroll
    for (int j = 0; j < 64; ++j) w[j] = wrow[j];

    const int xv0 = g ? 15 : 0;           // g0: v 0..14, g1: v 15..28
    const int xn  = g ? 14 : 15;
    float wx[15];
    #pragma unroll
    for (int j = 0; j < 15; ++j) wx[j] = (j < xn) ? We_ih[i * VV + xv0 + j] : 0.0f;

    const float bias = (g == 0) ? (be_ih[i] + be_hh[i]) : 0.0f;

    const float* xb = x + (size_t)b * SS * VV;

    if (g == 0) hbuf[0][i] = 0.0f;
    if (tid < 32) {
        xbuf[0][tid] = (tid < VV) ? xb[tid] : 0.0f;
        xbuf[1][tid] = 0.0f;                 // pad slots of buf1 (29..31) stay 0
    }
    __syncthreads();

    // ---- encoder scan, 2x unrolled ping-pong ----
#define ENC_STEP(CUR, NXT, T)                                              \
    {                                                                      \
        float xpre = 0.0f;                                                 \
        {                                                                  \
            int tn = (T) + 1; if (tn >= SS) tn = SS - 1;                   \
            if (g == 0 && i < VV) xpre = xb[tn * VV + i];                  \
        }                                                                  \
        float a0 = 0.f, a1 = 0.f, a2 = 0.f, a3 = 0.f;                      \
        const float* hb = &hbuf[CUR][g * 64];                              \
        _Pragma("unroll")                                                  \
        for (int j = 0; j < 64; j += 4) {                                  \
            a0 += w[j + 0] * hb[j + 0];                                    \
            a1 += w[j + 1] * hb[j + 1];                                    \
            a2 += w[j + 2] * hb[j + 2];                                    \
            a3 += w[j + 3] * hb[j + 3];                                    \
        }                                                                  \
        float accx = bias;                                                 \
        _Pragma("unroll")                                                  \
        for (int j = 0; j < 15; ++j) accx += wx[j] * xbuf[CUR][xv0 + j];   \
        float p = (a0 + a1) + (a2 + a3) + accx;                            \
        if (g) part[i] = p;                                                \
        __syncthreads();                                                   \
        if (g == 0) {                                                      \
            float hn = fast_tanh(p + part[i]);                             \
            hbuf[NXT][i] = hn;                                             \
            if (i < VV) xbuf[NXT][i] = xpre;                               \
        }                                                                  \
        __syncthreads();                                                   \
    }

    for (int t = 0; t < SS; t += 2) {
        ENC_STEP(0, 1, t)
        ENC_STEP(1, 0, t + 1)
    }
    // encoded vector in hbuf[0][0..127]; all threads past final barrier.

    // ---- decoder: single wave (threads 0..63), no barriers ----
    if (tid >= 64) return;
    const int lane = tid;
    const int r = (lane < VV) ? lane : (VV - 1);   // lanes >=29 mirror row 28 (identical values)

    // dec_in = encoded @ Wd_ih^T + bd_ih + bd_hh
    float di = bd_ih[r] + bd_hh[r];
    {
        const float* wdi = Wd_ih + r * HH;
        float d0 = 0.f, d1 = 0.f, d2 = 0.f, d3 = 0.f;
        #pragma unroll
        for (int j = 0; j < HH; j += 4) {
            d0 += wdi[j + 0] * hbuf[0][j + 0];
            d1 += wdi[j + 1] * hbuf[0][j + 1];
            d2 += wdi[j + 2] * hbuf[0][j + 2];
            d3 += wdi[j + 3] * hbuf[0][j + 3];
        }
        di += (d0 + d1) + (d2 + d3);
    }

    float wd[VV];
    {
        const float* wdr = Wd_hh + r * VV;
        #pragma unroll
        for (int j = 0; j < VV; ++j) wd[j] = wdr[j];
    }

    float hd = 0.0f;
    float* ob = out + (size_t)b * SS * VV;
    int t = 0;
    for (; t < SS; ++t) {
        float a0 = di, a1 = 0.f, a2 = 0.f, a3 = 0.f;
        #pragma unroll
        for (int j = 0; j < VV; j += 4) {
            a0 += wd[j] * __shfl(hd, j, 64);
            if (j + 1 < VV) a1 += wd[j + 1] * __shfl(hd, j + 1, 64);
            if (j + 2 < VV) a2 += wd[j + 2] * __shfl(hd, j + 2, 64);
            if (j + 3 < VV) a3 += wd[j + 3] * __shfl(hd, j + 3, 64);
        }
        float hn = fast_tanh((a0 + a1) + (a2 + a3));
        int conv = (fabsf(hn - hd) < 1e-6f) ? 1 : 0;
        hd = hn;
        if (lane < VV) ob[(size_t)t * VV + lane] = hn;
        if (__all(conv)) { ++t; break; }
    }

    // ---- fixed-point bulk fill for remaining steps ----
    if (t < SS) {
        // advance t to a multiple of 4 so flat offset t*29 is 16B-aligned
        // (29 mod 4 == 1  =>  (t*29) mod 4 == t mod 4)
        while (t & 3) {
            if (lane < VV) ob[(size_t)t * VV + lane] = hd;
            ++t;
        }
        if (t < SS) {
            // flat offsets f in [t*29, 2048*29), value(f) = h*[f mod 29].
            // 58 lanes x 4 floats = 232 per sweep; 232 % 29 == 0 and
            // 232 % 4 == 0, so each lane's phase (4*lane) % 29 is constant
            // across iterations, and the 4-aligned slots tile [f0, fend)
            // exactly (fend = 59392 is a multiple of 4) -- no tail.
            const int phi = (4 * lane) % VV;
            float4 v4;
            v4.x = __shfl(hd, phi, 64);
            v4.y = __shfl(hd, (phi + 1) % VV, 64);
            v4.z = __shfl(hd, (phi + 2) % VV, 64);
            v4.w = __shfl(hd, (phi + 3) % VV, 64);
            if (lane < 58) {
                const long fend = (long)SS * VV;
                for (long f = (long)t * VV + 4 * lane; f + 4 <= fend; f += 232) {
                    *reinterpret_cast<float4*>(ob + f) = v4;
                }
            }
        }
    }
}

extern "C" void kernel_launch(void* const* d_in, const int* in_sizes, int n_in,
                              void* d_out, int out_size, void* d_ws, size_t ws_size,
                              hipStream_t stream) {
    const float* x     = (const float*)d_in[0];
    const float* We_ih = (const float*)d_in[1];
    const float* We_hh = (const float*)d_in[2];
    const float* be_ih = (const float*)d_in[3];
    const float* be_hh = (const float*)d_in[4];
    const float* Wd_ih = (const float*)d_in[5];
    const float* Wd_hh = (const float*)d_in[6];
    const float* bd_ih = (const float*)d_in[7];
    const float* bd_hh = (const float*)d_in[8];
    float* out = (float*)d_out;

    rnn_fused<<<dim3(BB), dim3(256), 0, stream>>>(
        x, We_ih, We_hh, be_ih, be_hh, Wd_ih, Wd_hh, bd_ih, bd_hh, out);
}